// Round 1
// baseline (302.065 us; speedup 1.0000x reference)
//
#include <hip/hip_runtime.h>
#include <math.h>

#define NN 131072
#define KK 27
#define FIN 3
#define FOUT 32
#define EPS 1e-5f

// Phase 1: h = silu(bn1(einsum(x_feats[nbr_idx], w1)))  -> d_ws [N,32] f32
__global__ __launch_bounds__(256) void conv1_kernel(
    const float* __restrict__ x_feats,   // [N,3]
    const int*   __restrict__ nbr_idx,   // [N,27]
    const float* __restrict__ w1,        // [27,3,32]
    const float* __restrict__ g1,  const float* __restrict__ b1,
    const float* __restrict__ m1,  const float* __restrict__ v1,
    float* __restrict__ h_out)           // [N,32]
{
    const int n = blockIdx.x * blockDim.x + threadIdx.x;
    if (n >= NN) return;

    float acc[FOUT];
#pragma unroll
    for (int o = 0; o < FOUT; ++o) acc[o] = 0.f;

    const int* nb = nbr_idx + (size_t)n * KK;
#pragma unroll 1
    for (int k = 0; k < KK; ++k) {
        const int idx = nb[k];
        const float* xr = x_feats + (size_t)idx * FIN;
        const float x0 = xr[0], x1 = xr[1], x2 = xr[2];
        const float* w = w1 + k * FIN * FOUT;   // wave-uniform -> s_load
#pragma unroll
        for (int o = 0; o < FOUT; ++o) {
            float a = acc[o];
            a = fmaf(x0, w[o],            a);
            a = fmaf(x1, w[FOUT + o],     a);
            a = fmaf(x2, w[2 * FOUT + o], a);
            acc[o] = a;
        }
    }

    float* hr = h_out + (size_t)n * FOUT;
#pragma unroll
    for (int o = 0; o < FOUT; ++o) {
        const float sc = g1[o] * rsqrtf(v1[o] + EPS);
        float v = (acc[o] - m1[o]) * sc + b1[o];
        v = v / (1.f + __expf(-v));          // silu
        hr[o] = v;
    }
}

// Phase 2: x_out = einsum(h[nbr_idx], w2); z = relu(bn(z @ mlp_w + b));
// fused = x_out + z, written to both output slots.
__global__ __launch_bounds__(256) void conv2_kernel(
    const float* __restrict__ h,         // [N,32]
    const int*   __restrict__ nbr_idx,   // [N,27]
    const float* __restrict__ w2,        // [27,32,32]
    const float* __restrict__ z_feats,   // [N,3]
    const float* __restrict__ mlp_w,     // [3,32]
    const float* __restrict__ mlp_b,
    const float* __restrict__ mg, const float* __restrict__ mbeta,
    const float* __restrict__ mm, const float* __restrict__ mv,
    float* __restrict__ out)             // [2,N,32]
{
    const int n = blockIdx.x * blockDim.x + threadIdx.x;
    if (n >= NN) return;

    float acc[FOUT];
#pragma unroll
    for (int o = 0; o < FOUT; ++o) acc[o] = 0.f;

    const int* nb = nbr_idx + (size_t)n * KK;
#pragma unroll 1
    for (int k = 0; k < KK; ++k) {
        const int idx = nb[k];
        const float4* hr = (const float4*)(h + (size_t)idx * FOUT);
        const float* w = w2 + k * FOUT * FOUT;   // wave-uniform -> s_load
#pragma unroll
        for (int f4 = 0; f4 < FOUT / 4; ++f4) {
            const float4 hv = hr[f4];
            const float* wr = w + (f4 * 4) * FOUT;
#pragma unroll
            for (int o = 0; o < FOUT; ++o) {
                float a = acc[o];
                a = fmaf(hv.x, wr[o],            a);
                a = fmaf(hv.y, wr[FOUT + o],     a);
                a = fmaf(hv.z, wr[2 * FOUT + o], a);
                a = fmaf(hv.w, wr[3 * FOUT + o], a);
                acc[o] = a;
            }
        }
    }

    // point branch
    const float z0 = z_feats[(size_t)n * 3 + 0];
    const float z1 = z_feats[(size_t)n * 3 + 1];
    const float z2 = z_feats[(size_t)n * 3 + 2];

    float* o0 = out + (size_t)n * FOUT;
    float* o1 = out + (size_t)NN * FOUT + (size_t)n * FOUT;
#pragma unroll
    for (int o = 0; o < FOUT; ++o) {
        float z = mlp_b[o];
        z = fmaf(z0, mlp_w[o],            z);
        z = fmaf(z1, mlp_w[FOUT + o],     z);
        z = fmaf(z2, mlp_w[2 * FOUT + o], z);
        const float sc = mg[o] * rsqrtf(mv[o] + EPS);
        z = (z - mm[o]) * sc + mbeta[o];
        z = fmaxf(z, 0.f);
        const float v = acc[o] + z;
        o0[o] = v;
        o1[o] = v;
    }
}

extern "C" void kernel_launch(void* const* d_in, const int* in_sizes, int n_in,
                              void* d_out, int out_size, void* d_ws, size_t ws_size,
                              hipStream_t stream) {
    const float* x_feats = (const float*)d_in[0];
    const float* z_feats = (const float*)d_in[1];
    const int*   nbr_idx = (const int*)d_in[2];
    const float* w1      = (const float*)d_in[3];
    const float* bn1_g   = (const float*)d_in[4];
    const float* bn1_b   = (const float*)d_in[5];
    const float* bn1_m   = (const float*)d_in[6];
    const float* bn1_v   = (const float*)d_in[7];
    const float* w2      = (const float*)d_in[8];
    const float* mlp_w   = (const float*)d_in[9];
    const float* mlp_b   = (const float*)d_in[10];
    const float* mlp_g   = (const float*)d_in[11];
    const float* mlp_be  = (const float*)d_in[12];
    const float* mlp_m   = (const float*)d_in[13];
    const float* mlp_v   = (const float*)d_in[14];

    float* h = (float*)d_ws;             // N*32 f32 = 16 MiB scratch
    float* out = (float*)d_out;

    dim3 block(256);
    dim3 grid((NN + 255) / 256);

    conv1_kernel<<<grid, block, 0, stream>>>(x_feats, nbr_idx, w1,
                                             bn1_g, bn1_b, bn1_m, bn1_v, h);
    conv2_kernel<<<grid, block, 0, stream>>>(h, nbr_idx, w2, z_feats,
                                             mlp_w, mlp_b, mlp_g, mlp_be,
                                             mlp_m, mlp_v, out);
}